// Round 5
// baseline (1115.278 us; speedup 1.0000x reference)
//
#include <hip/hip_runtime.h>
#include <hip/hip_bf16.h>

// Shapes (fixed by the reference):
//   center (16,1024,3) f32 | cam_posquat (16,4,7) | intrinsic (16,4,6)
//   img_feat (16,4,64,64,256) f32 (256 MiB) | z (16,1024,1,256)
//   w_attn (256,8) b_attn (8) w_feat (256,8,128) b_feat (8,128)
//   w_out (1024,256) b_out (256) -> out (16,1024,1,256) f32
//
// Algebra: comb[h,d] = (sum_c aw[c,h]*feats[c,:]) @ w_feat[:,h,d]
//                      + (sum_c aw[c,h]) * b_feat[h,d]
// folds the camera dim out of the big einsum (4x FLOP cut).
//
// Block = 256 threads handles P=8 points: amortizes w_feat/w_out reads
// (2 MiB per block, L2-resident) across 8 points via LDS-staged bf16
// wf[h][f][p] / comb[k][p] (p-contiguous -> one ds_read_b128 feeds all 8
// point-accumulators; broadcast reads, no bank conflicts).

namespace {
constexpr int kNB = 16, kNO = 1024, kNC = 4, kNF = 256, kNH = 8;
constexpr int kD2 = 128, kND = 256, kNI = 64, kNJ = 64, kP = 8;

typedef __attribute__((ext_vector_type(8))) unsigned short ushortx8;

__device__ __forceinline__ float bf2f(unsigned short u) {
  return __uint_as_float(((unsigned int)u) << 16);
}
__device__ __forceinline__ unsigned short f2bf(float f) {
  unsigned int x = __float_as_uint(f);
  x += 0x7FFFu + ((x >> 16) & 1u);  // round-to-nearest-even
  return (unsigned short)(x >> 16);
}
}  // namespace

extern "C" __global__ void __launch_bounds__(256, 2)
fused_dcattn(const float* __restrict__ center,
             const float* __restrict__ cam_posquat,
             const float* __restrict__ intrinsic,
             const float* __restrict__ img_feat,
             const float* __restrict__ zin,
             const float* __restrict__ w_attn,
             const float* __restrict__ b_attn,
             const float* __restrict__ w_feat,
             const float* __restrict__ b_feat,
             const float* __restrict__ w_out,
             const float* __restrict__ b_out,
             float* __restrict__ out) {
  __shared__ int            s_idx[kP][kNC][4];
  __shared__ float          s_wt [kP][kNC][4];
  __shared__ float          s_feat[kNC][kNF];
  __shared__ float          s_aw [kNC][kNH];
  __shared__ float          s_s  [kP][kNH];
  __shared__ __align__(16) unsigned short s_wf [kNH][kNF][kP];    // bf16 (32 KiB)
  __shared__ __align__(16) unsigned short s_comb[kNH * kD2][kP];  // bf16 (16 KiB)

  const int tid = threadIdx.x;
  const int blk = blockIdx.x;
  const int b   = blk / (kNO / kP);
  const int o0  = (blk % (kNO / kP)) * kP;

  // ---- projection + bilinear tap setup: one thread per (point, cam) ----
  if (tid < kP * kNC) {
    const int p = tid >> 2, c = tid & 3;
    const float* pq = cam_posquat + (b * kNC + c) * 7;
    const float* ct = center + (size_t)(b * kNO + o0 + p) * 3;
    const float* it = intrinsic + (b * kNC + c) * 6;

    const float rx = ct[0] - pq[0], ry = ct[1] - pq[1], rz = ct[2] - pq[2];
    float qx = pq[3], qy = pq[4], qz = pq[5], qw = pq[6];
    const float qn = 1.f / sqrtf(qx * qx + qy * qy + qz * qz + qw * qw);
    qx *= qn; qy *= qn; qz *= qn; qw *= qn;

    const float R00 = 1.f - 2.f * (qy * qy + qz * qz);
    const float R01 = 2.f * (qx * qy - qz * qw);
    const float R02 = 2.f * (qx * qz + qy * qw);
    const float R10 = 2.f * (qx * qy + qz * qw);
    const float R11 = 1.f - 2.f * (qx * qx + qz * qz);
    const float R12 = 2.f * (qy * qz - qx * qw);
    const float R20 = 2.f * (qx * qz - qy * qw);
    const float R21 = 2.f * (qy * qz + qx * qw);
    const float R22 = 1.f - 2.f * (qx * qx + qy * qy);

    // p_cam = R^T * rel
    const float pcx = R00 * rx + R10 * ry + R20 * rz;
    const float pcy = R01 * rx + R11 * ry + R21 * rz;
    const float pcz = R02 * rx + R12 * ry + R22 * rz;
    const float zc  = fmaxf(pcz, 0.01f);

    const float u = it[2] * pcx / zc + it[4];
    const float v = it[3] * pcy / zc + it[5];
    // px_ctn = (v,u) / (W,H) * (NI,NJ)  -- ref pairs (v with intr[0], u with intr[1])
    const float row = v / it[0] * (float)kNI;
    const float col = u / it[1] * (float)kNJ;

    const int   pr = (int)floorf(row);
    const int   pc = (int)floorf(col);
    const float offr = fminf(fmaxf(row - 0.5f, 0.f), (float)(kNI - 1));
    const float offc = fminf(fmaxf(col - 0.5f, 0.f), (float)(kNJ - 1));

    float wv[4];
    int   iv[4];
    float wsum = 0.f;
#pragma unroll
    for (int t = 0; t < 4; ++t) {
      const int sr = t >> 1, sc = t & 1;
      const int prr = min(max(pr + sr, 0), kNI - 1);
      const int pcc = min(max(pc + sc, 0), kNJ - 1);
      iv[t] = prr * kNJ + pcc;
      const float rr = fabsf(offr - (float)(pr + 1 - sr)) + 0.01f;
      const float rc = fabsf(offc - (float)(pc + 1 - sc)) + 0.01f;
      wv[t] = rr * rc;
      wsum += wv[t];
    }
    const float inv = 1.f / wsum;
#pragma unroll
    for (int t = 0; t < 4; ++t) {
      s_idx[p][c][t] = iv[t];
      s_wt [p][c][t] = wv[t] * inv;
    }
  }

  // ---- phase A: per point, gather feats -> aw -> softmax -> wf ----
  for (int p = 0; p < kP; ++p) {
    __syncthreads();  // protects s_feat/s_aw reuse across points
    {
      const int f = tid;
#pragma unroll
      for (int c = 0; c < kNC; ++c) {
        const float* base =
            img_feat + (size_t)(b * kNC + c) * (kNI * kNJ) * kNF;
        float acc = 0.f;
#pragma unroll
        for (int t = 0; t < 4; ++t)
          acc += s_wt[p][c][t] * base[(size_t)s_idx[p][c][t] * kNF + f];
        s_feat[c][f] = acc;
      }
    }
    __syncthreads();
    {  // aw[c][h]: 32 groups of 8 lanes reduce over f
      const int g = tid >> 3, l = tid & 7;
      const int c = g >> 3, h = g & 7;
      float part = 0.f;
      for (int f = l; f < kNF; f += 8)
        part += s_feat[c][f] * w_attn[f * kNH + h];
      part += __shfl_xor(part, 1, 8);
      part += __shfl_xor(part, 2, 8);
      part += __shfl_xor(part, 4, 8);
      if (l == 0) s_aw[c][h] = part + b_attn[h];
    }
    __syncthreads();
    if (tid < kNC) {  // softmax over h for one camera
      const int c = tid;
      float m = s_aw[c][0];
#pragma unroll
      for (int h = 1; h < kNH; ++h) m = fmaxf(m, s_aw[c][h]);
      float e[kNH], sum = 0.f;
#pragma unroll
      for (int h = 0; h < kNH; ++h) { e[h] = expf(s_aw[c][h] - m); sum += e[h]; }
      const float inv = 1.f / sum;
#pragma unroll
      for (int h = 0; h < kNH; ++h) s_aw[c][h] = e[h] * inv;
    }
    __syncthreads();
    {  // wf[h][f][p] = sum_c aw[c,h]*feats[c,f]
      const int f = tid;
#pragma unroll
      for (int h = 0; h < kNH; ++h) {
        float v = 0.f;
#pragma unroll
        for (int c = 0; c < kNC; ++c) v += s_aw[c][h] * s_feat[c][f];
        s_wf[h][f][p] = f2bf(v);
      }
      if (tid < kNH) {
        float ssum = 0.f;
#pragma unroll
        for (int c = 0; c < kNC; ++c) ssum += s_aw[c][tid];
        s_s[p][tid] = ssum;
      }
    }
  }
  __syncthreads();

  // ---- phase B: comb[p][h][d] = wf[p][h][:]@w_feat[:,h,d] + s*b_feat ----
  {
    const int h  = tid >> 5;
    const int d0 = (tid & 31) * 4;
    float acc0[kP], acc1[kP], acc2[kP], acc3[kP];
#pragma unroll
    for (int p = 0; p < kP; ++p) acc0[p] = acc1[p] = acc2[p] = acc3[p] = 0.f;
#pragma unroll 4
    for (int f = 0; f < kNF; ++f) {
      const float4 wv =
          *(const float4*)(w_feat + ((size_t)f * kNH + h) * kD2 + d0);
      const ushortx8 a8 = *(const ushortx8*)&s_wf[h][f][0];
#pragma unroll
      for (int p = 0; p < kP; ++p) {
        const float a = bf2f(a8[p]);
        acc0[p] += a * wv.x;
        acc1[p] += a * wv.y;
        acc2[p] += a * wv.z;
        acc3[p] += a * wv.w;
      }
    }
    const float4 bf = *(const float4*)(b_feat + h * kD2 + d0);
    const int k0 = h * kD2 + d0;
#pragma unroll
    for (int p = 0; p < kP; ++p) {
      const float ss = s_s[p][h];
      s_comb[k0 + 0][p] = f2bf(acc0[p] + ss * bf.x);
      s_comb[k0 + 1][p] = f2bf(acc1[p] + ss * bf.y);
      s_comb[k0 + 2][p] = f2bf(acc2[p] + ss * bf.z);
      s_comb[k0 + 3][p] = f2bf(acc3[p] + ss * bf.w);
    }
  }
  __syncthreads();

  // ---- phase C: out[p][nd] = z + comb[p]@w_out[:,nd] + b_out[nd] ----
  {
    const int nd = tid;
    float acc[kP];
    const float bo = b_out[nd];
#pragma unroll
    for (int p = 0; p < kP; ++p) acc[p] = bo;
#pragma unroll 2
    for (int k = 0; k < kNH * kD2; ++k) {
      const float w = w_out[(size_t)k * kND + nd];
      const ushortx8 c8 = *(const ushortx8*)&s_comb[k][0];
#pragma unroll
      for (int p = 0; p < kP; ++p) acc[p] += bf2f(c8[p]) * w;
    }
#pragma unroll
    for (int p = 0; p < kP; ++p) {
      const size_t oi = ((size_t)(b * kNO + o0 + p)) * kND + nd;
      out[oi] = zin[oi] + acc[p];
    }
  }
}

extern "C" void kernel_launch(void* const* d_in, const int* in_sizes, int n_in,
                              void* d_out, int out_size, void* d_ws,
                              size_t ws_size, hipStream_t stream) {
  (void)in_sizes; (void)n_in; (void)out_size; (void)d_ws; (void)ws_size;
  const float* center      = (const float*)d_in[0];
  const float* cam_posquat = (const float*)d_in[1];
  const float* intrinsic   = (const float*)d_in[2];
  const float* img_feat    = (const float*)d_in[3];
  const float* zin         = (const float*)d_in[4];
  const float* w_attn      = (const float*)d_in[5];
  const float* b_attn      = (const float*)d_in[6];
  const float* w_feat      = (const float*)d_in[7];
  const float* b_feat      = (const float*)d_in[8];
  const float* w_out       = (const float*)d_in[9];
  const float* b_out       = (const float*)d_in[10];

  const dim3 grid(kNB * kNO / kP);  // 2048 blocks
  fused_dcattn<<<grid, 256, 0, stream>>>(center, cam_posquat, intrinsic,
                                         img_feat, zin, w_attn, b_attn, w_feat,
                                         b_feat, w_out, b_out, (float*)d_out);
}

// Round 7
// 805.632 us; speedup vs baseline: 1.3844x; 1.3844x over previous
//
#include <hip/hip_runtime.h>
#include <hip/hip_bf16.h>

// Shapes (fixed by the reference):
//   center (16,1024,3) f32 | cam_posquat (16,4,7) | intrinsic (16,4,6)
//   img_feat (16,4,64,64,256) f32 (256 MiB) | z (16,1024,1,256)
//   w_attn (256,8) b_attn (8) w_feat (256,8,128) b_feat (8,128)
//   w_out (1024,256) b_out (256) -> out (16,1024,1,256) f32
//
// Algebra: comb[h,d] = (sum_c aw[c,h]*feats[c,:]) @ w_feat[:,h,d]
//                      + (sum_c aw[c,h]) * b_feat[h,d]
// folds the camera dim out of the big einsum (4x FLOP cut).
//
// R5 diagnosis: latency-bound (VALUBusy 39%, HBM 0.9%, occ 23.6%).
// Phase C: 1024 L2 loads with unroll 2 -> ~2 in flight -> ~100K cyc/block.
// Fix: unroll 8 (B and C) + s_idx packed to ushort (saves 512 B LDS ->
// 54,272 B <= 54,613 B boundary -> 3 blocks/CU instead of 2).

namespace {
constexpr int kNB = 16, kNO = 1024, kNC = 4, kNF = 256, kNH = 8;
constexpr int kD2 = 128, kND = 256, kNI = 64, kNJ = 64, kP = 8;

typedef __attribute__((ext_vector_type(8))) unsigned short ushortx8;

__device__ __forceinline__ float bf2f(unsigned short u) {
  return __uint_as_float(((unsigned int)u) << 16);
}
__device__ __forceinline__ unsigned short f2bf(float f) {
  unsigned int x = __float_as_uint(f);
  x += 0x7FFFu + ((x >> 16) & 1u);  // round-to-nearest-even
  return (unsigned short)(x >> 16);
}
}  // namespace

extern "C" __global__ void __launch_bounds__(256, 3)
fused_dcattn(const float* __restrict__ center,
             const float* __restrict__ cam_posquat,
             const float* __restrict__ intrinsic,
             const float* __restrict__ img_feat,
             const float* __restrict__ zin,
             const float* __restrict__ w_attn,
             const float* __restrict__ b_attn,
             const float* __restrict__ w_feat,
             const float* __restrict__ b_feat,
             const float* __restrict__ w_out,
             const float* __restrict__ b_out,
             float* __restrict__ out) {
  __shared__ unsigned short s_idx[kP][kNC][4];  // tap indices < 4096
  __shared__ float          s_wt [kP][kNC][4];
  __shared__ float          s_feat[kNC][kNF];
  __shared__ float          s_aw [kNC][kNH];
  __shared__ float          s_s  [kP][kNH];
  __shared__ __align__(16) unsigned short s_wf [kNH][kNF][kP];    // bf16 (32 KiB)
  __shared__ __align__(16) unsigned short s_comb[kNH * kD2][kP];  // bf16 (16 KiB)

  const int tid = threadIdx.x;
  const int blk = blockIdx.x;
  const int b   = blk / (kNO / kP);
  const int o0  = (blk % (kNO / kP)) * kP;

  // ---- projection + bilinear tap setup: one thread per (point, cam) ----
  if (tid < kP * kNC) {
    const int p = tid >> 2, c = tid & 3;
    const float* pq = cam_posquat + (b * kNC + c) * 7;
    const float* ct = center + (size_t)(b * kNO + o0 + p) * 3;
    const float* it = intrinsic + (b * kNC + c) * 6;

    const float rx = ct[0] - pq[0], ry = ct[1] - pq[1], rz = ct[2] - pq[2];
    float qx = pq[3], qy = pq[4], qz = pq[5], qw = pq[6];
    const float qn = 1.f / sqrtf(qx * qx + qy * qy + qz * qz + qw * qw);
    qx *= qn; qy *= qn; qz *= qn; qw *= qn;

    const float R00 = 1.f - 2.f * (qy * qy + qz * qz);
    const float R01 = 2.f * (qx * qy - qz * qw);
    const float R02 = 2.f * (qx * qz + qy * qw);
    const float R10 = 2.f * (qx * qy + qz * qw);
    const float R11 = 1.f - 2.f * (qx * qx + qz * qz);
    const float R12 = 2.f * (qy * qz - qx * qw);
    const float R20 = 2.f * (qx * qz - qy * qw);
    const float R21 = 2.f * (qy * qz + qx * qw);
    const float R22 = 1.f - 2.f * (qx * qx + qy * qy);

    // p_cam = R^T * rel
    const float pcx = R00 * rx + R10 * ry + R20 * rz;
    const float pcy = R01 * rx + R11 * ry + R21 * rz;
    const float pcz = R02 * rx + R12 * ry + R22 * rz;
    const float zc  = fmaxf(pcz, 0.01f);

    const float u = it[2] * pcx / zc + it[4];
    const float v = it[3] * pcy / zc + it[5];
    // px_ctn = (v,u) / (W,H) * (NI,NJ)
    const float row = v / it[0] * (float)kNI;
    const float col = u / it[1] * (float)kNJ;

    const int   pr = (int)floorf(row);
    const int   pc = (int)floorf(col);
    const float offr = fminf(fmaxf(row - 0.5f, 0.f), (float)(kNI - 1));
    const float offc = fminf(fmaxf(col - 0.5f, 0.f), (float)(kNJ - 1));

    float wv[4];
    int   iv[4];
    float wsum = 0.f;
#pragma unroll
    for (int t = 0; t < 4; ++t) {
      const int sr = t >> 1, sc = t & 1;
      const int prr = min(max(pr + sr, 0), kNI - 1);
      const int pcc = min(max(pc + sc, 0), kNJ - 1);
      iv[t] = prr * kNJ + pcc;
      const float rr = fabsf(offr - (float)(pr + 1 - sr)) + 0.01f;
      const float rc = fabsf(offc - (float)(pc + 1 - sc)) + 0.01f;
      wv[t] = rr * rc;
      wsum += wv[t];
    }
    const float inv = 1.f / wsum;
#pragma unroll
    for (int t = 0; t < 4; ++t) {
      s_idx[p][c][t] = (unsigned short)iv[t];
      s_wt [p][c][t] = wv[t] * inv;
    }
  }

  // ---- phase A: per point, gather feats -> aw -> softmax -> wf ----
  for (int p = 0; p < kP; ++p) {
    __syncthreads();  // protects s_feat/s_aw reuse across points
    {
      const int f = tid;
#pragma unroll
      for (int c = 0; c < kNC; ++c) {
        const float* base =
            img_feat + (size_t)(b * kNC + c) * (kNI * kNJ) * kNF;
        float acc = 0.f;
#pragma unroll
        for (int t = 0; t < 4; ++t)
          acc += s_wt[p][c][t] * base[(size_t)s_idx[p][c][t] * kNF + f];
        s_feat[c][f] = acc;
      }
    }
    __syncthreads();
    {  // aw[c][h]: 32 groups of 8 lanes reduce over f
      const int g = tid >> 3, l = tid & 7;
      const int c = g >> 3, h = g & 7;
      float part = 0.f;
      for (int f = l; f < kNF; f += 8)
        part += s_feat[c][f] * w_attn[f * kNH + h];
      part += __shfl_xor(part, 1, 8);
      part += __shfl_xor(part, 2, 8);
      part += __shfl_xor(part, 4, 8);
      if (l == 0) s_aw[c][h] = part + b_attn[h];
    }
    __syncthreads();
    if (tid < kNC) {  // softmax over h for one camera
      const int c = tid;
      float m = s_aw[c][0];
#pragma unroll
      for (int h = 1; h < kNH; ++h) m = fmaxf(m, s_aw[c][h]);
      float e[kNH], sum = 0.f;
#pragma unroll
      for (int h = 0; h < kNH; ++h) { e[h] = expf(s_aw[c][h] - m); sum += e[h]; }
      const float inv = 1.f / sum;
#pragma unroll
      for (int h = 0; h < kNH; ++h) s_aw[c][h] = e[h] * inv;
    }
    __syncthreads();
    {  // wf[h][f][p] = sum_c aw[c,h]*feats[c,f]
      const int f = tid;
#pragma unroll
      for (int h = 0; h < kNH; ++h) {
        float v = 0.f;
#pragma unroll
        for (int c = 0; c < kNC; ++c) v += s_aw[c][h] * s_feat[c][f];
        s_wf[h][f][p] = f2bf(v);
      }
      if (tid < kNH) {
        float ssum = 0.f;
#pragma unroll
        for (int c = 0; c < kNC; ++c) ssum += s_aw[c][tid];
        s_s[p][tid] = ssum;
      }
    }
  }
  __syncthreads();

  // ---- phase B: comb[p][h][d] = wf[p][h][:]@w_feat[:,h,d] + s*b_feat ----
  {
    const int h  = tid >> 5;
    const int d0 = (tid & 31) * 4;
    float acc0[kP], acc1[kP], acc2[kP], acc3[kP];
#pragma unroll
    for (int p = 0; p < kP; ++p) acc0[p] = acc1[p] = acc2[p] = acc3[p] = 0.f;
#pragma unroll 8
    for (int f = 0; f < kNF; ++f) {
      const float4 wv =
          *(const float4*)(w_feat + ((size_t)f * kNH + h) * kD2 + d0);
      const ushortx8 a8 = *(const ushortx8*)&s_wf[h][f][0];
#pragma unroll
      for (int p = 0; p < kP; ++p) {
        const float a = bf2f(a8[p]);
        acc0[p] += a * wv.x;
        acc1[p] += a * wv.y;
        acc2[p] += a * wv.z;
        acc3[p] += a * wv.w;
      }
    }
    const float4 bf = *(const float4*)(b_feat + h * kD2 + d0);
    const int k0 = h * kD2 + d0;
#pragma unroll
    for (int p = 0; p < kP; ++p) {
      const float ss = s_s[p][h];
      s_comb[k0 + 0][p] = f2bf(acc0[p] + ss * bf.x);
      s_comb[k0 + 1][p] = f2bf(acc1[p] + ss * bf.y);
      s_comb[k0 + 2][p] = f2bf(acc2[p] + ss * bf.z);
      s_comb[k0 + 3][p] = f2bf(acc3[p] + ss * bf.w);
    }
  }
  __syncthreads();

  // ---- phase C: out[p][nd] = z + comb[p]@w_out[:,nd] + b_out[nd] ----
  {
    const int nd = tid;
    float acc[kP];
    const float bo = b_out[nd];
#pragma unroll
    for (int p = 0; p < kP; ++p) acc[p] = bo;
#pragma unroll 8
    for (int k = 0; k < kNH * kD2; ++k) {
      const float w = w_out[(size_t)k * kND + nd];
      const ushortx8 c8 = *(const ushortx8*)&s_comb[k][0];
#pragma unroll
      for (int p = 0; p < kP; ++p) acc[p] += bf2f(c8[p]) * w;
    }
#pragma unroll
    for (int p = 0; p < kP; ++p) {
      const size_t oi = ((size_t)(b * kNO + o0 + p)) * kND + nd;
      out[oi] = zin[oi] + acc[p];
    }
  }
}

extern "C" void kernel_launch(void* const* d_in, const int* in_sizes, int n_in,
                              void* d_out, int out_size, void* d_ws,
                              size_t ws_size, hipStream_t stream) {
  (void)in_sizes; (void)n_in; (void)out_size; (void)d_ws; (void)ws_size;
  const float* center      = (const float*)d_in[0];
  const float* cam_posquat = (const float*)d_in[1];
  const float* intrinsic   = (const float*)d_in[2];
  const float* img_feat    = (const float*)d_in[3];
  const float* zin         = (const float*)d_in[4];
  const float* w_attn      = (const float*)d_in[5];
  const float* b_attn      = (const float*)d_in[6];
  const float* w_feat      = (const float*)d_in[7];
  const float* b_feat      = (const float*)d_in[8];
  const float* w_out       = (const float*)d_in[9];
  const float* b_out       = (const float*)d_in[10];

  const dim3 grid(kNB * kNO / kP);  // 2048 blocks
  fused_dcattn<<<grid, 256, 0, stream>>>(center, cam_posquat, intrinsic,
                                         img_feat, zin, w_attn, b_attn, w_feat,
                                         b_feat, w_out, b_out, (float*)d_out);
}